// Round 1
// baseline (715.716 us; speedup 1.0000x reference)
//
#include <hip/hip_runtime.h>
#include <math.h>
#include <float.h>

#define BB 8
#define FF 1024
#define NJ 17
#define CH 512
#define TOK 81
#define NT 16            // F / 64 column tiles
#define SQRT_C 22.627416997969522f   // sqrt(512)

// ---------------- kernel 1: mean over joints + row sumsq ----------------
__global__ __launch_bounds__(128) void pool_kernel(const float* __restrict__ x,
                                                   float* __restrict__ xknn,
                                                   float* __restrict__ sq) {
    const int row = blockIdx.x;          // b*FF + f
    const int t = threadIdx.x;           // 0..127, each owns 4 channels
    const float* px = x + (size_t)row * NJ * CH + t * 4;
    float4 acc = make_float4(0.f, 0.f, 0.f, 0.f);
    for (int n = 0; n < NJ; ++n) {
        const float4 v = *(const float4*)(px + (size_t)n * CH);
        acc.x += v.x; acc.y += v.y; acc.z += v.z; acc.w += v.w;
    }
    acc.x /= 17.0f; acc.y /= 17.0f; acc.z /= 17.0f; acc.w /= 17.0f;
    *(float4*)(xknn + (size_t)row * CH + t * 4) = acc;
    float s = acc.x * acc.x + acc.y * acc.y + acc.z * acc.z + acc.w * acc.w;
    for (int off = 32; off > 0; off >>= 1) s += __shfl_down(s, off);
    __shared__ float wsum[2];
    if ((t & 63) == 0) wsum[t >> 6] = s;
    __syncthreads();
    if (t == 0) sq[row] = wsum[0] + wsum[1];
}

__device__ inline void merge2(float& lo0, float& lo1, float c0, float c1) {
    // two smallest of {lo0<=lo1, c0<=c1}
    float n0 = fminf(lo0, c0);
    float n1 = fminf(fmaxf(lo0, c0), fminf(lo1, c1));
    lo0 = n0; lo1 = n1;
}

// ---------------- kernel 2: pass A — dist tile + two-smallest/rowmax partials ----
__global__ __launch_bounds__(256) void passA_kernel(const float* __restrict__ xknn,
                                                    const float* __restrict__ sq,
                                                    float2* __restrict__ p2,
                                                    float* __restrict__ pmax) {
    const int ct = blockIdx.x, rt = blockIdx.y, b = blockIdx.z;
    const int tid = threadIdx.x;
    const int tx = tid & 15, ty = tid >> 4;
    __shared__ float As[16][68];
    __shared__ float Bs[16][68];
    __shared__ float redlo[64][16], redhi[64][16], redmx[64][16];

    const float* Ab = xknn + ((size_t)b * FF + rt * 64) * CH;
    const float* Bb = xknn + ((size_t)b * FF + ct * 64) * CH;
    const int lr = tid >> 2;           // 0..63 row in tile
    const int lk = (tid & 3) * 4;      // 0,4,8,12
    float acc[4][4] = {};
    for (int kt = 0; kt < CH; kt += 16) {
        float4 a = *(const float4*)(Ab + (size_t)lr * CH + kt + lk);
        float4 bv = *(const float4*)(Bb + (size_t)lr * CH + kt + lk);
        __syncthreads();
        As[lk + 0][lr] = a.x;  As[lk + 1][lr] = a.y;  As[lk + 2][lr] = a.z;  As[lk + 3][lr] = a.w;
        Bs[lk + 0][lr] = bv.x; Bs[lk + 1][lr] = bv.y; Bs[lk + 2][lr] = bv.z; Bs[lk + 3][lr] = bv.w;
        __syncthreads();
        for (int kk = 0; kk < 16; ++kk) {
            const float4 av = *(const float4*)&As[kk][ty * 4];
            const float4 bw = *(const float4*)&Bs[kk][tx * 4];
            const float am[4] = {av.x, av.y, av.z, av.w};
            const float bn[4] = {bw.x, bw.y, bw.z, bw.w};
            for (int m = 0; m < 4; ++m)
                for (int n = 0; n < 4; ++n)
                    acc[m][n] = fmaf(am[m], bn[n], acc[m][n]);
        }
    }
    float sqa[4], sqb[4];
    for (int m = 0; m < 4; ++m) sqa[m] = sq[b * FF + rt * 64 + ty * 4 + m];
    for (int n = 0; n < 4; ++n) sqb[n] = sq[b * FF + ct * 64 + tx * 4 + n];

    for (int m = 0; m < 4; ++m) {
        float lo0 = FLT_MAX, lo1 = FLT_MAX, mx = -FLT_MAX;
        for (int n = 0; n < 4; ++n) {
            float d2 = sqa[m] + sqb[n] - 2.0f * acc[m][n];
            float dist = sqrtf(fmaxf(d2, 0.0f)) / SQRT_C;
            mx = fmaxf(mx, dist);
            merge2(lo0, lo1, dist, FLT_MAX);
        }
        redlo[ty * 4 + m][tx] = lo0;
        redhi[ty * 4 + m][tx] = lo1;
        redmx[ty * 4 + m][tx] = mx;
    }
    __syncthreads();
    if (tid < 64) {
        float lo0 = FLT_MAX, lo1 = FLT_MAX, mx = -FLT_MAX;
        for (int j = 0; j < 16; ++j) {
            merge2(lo0, lo1, redlo[tid][j], redhi[tid][j]);
            mx = fmaxf(mx, redmx[tid][j]);
        }
        const int row = rt * 64 + tid;
        p2[((size_t)b * FF + row) * NT + ct] = make_float2(lo0, lo1);
        pmax[((size_t)b * FF + row) * NT + ct] = mx;
    }
}

// ---------------- kernel 3: combine partials -> density, rowmax ----------------
__global__ __launch_bounds__(256) void reduceA_kernel(const float2* __restrict__ p2,
                                                      const float* __restrict__ pmax,
                                                      const float* __restrict__ noise,
                                                      float* __restrict__ density,
                                                      float* __restrict__ rowmax) {
    const int r = blockIdx.x * 256 + threadIdx.x;
    if (r >= BB * FF) return;
    float lo0 = FLT_MAX, lo1 = FLT_MAX, mx = -FLT_MAX;
    for (int j = 0; j < NT; ++j) {
        float2 c = p2[(size_t)r * NT + j];
        merge2(lo0, lo1, c.x, c.y);
        mx = fmaxf(mx, pmax[(size_t)r * NT + j]);
    }
    float dens = expf(-((lo0 * lo0 + lo1 * lo1) * 0.5f)) + noise[r] * 1e-6f;
    density[r] = dens;
    rowmax[r] = mx;
}

// ---------------- kernel 4: per-batch max distance ----------------
__global__ __launch_bounds__(256) void batchmax_kernel(const float* __restrict__ rowmax,
                                                       float* __restrict__ distmax) {
    const int b = blockIdx.x, t = threadIdx.x;
    float mx = -FLT_MAX;
    for (int j = t; j < FF; j += 256) mx = fmaxf(mx, rowmax[b * FF + j]);
    for (int off = 32; off > 0; off >>= 1) mx = fmaxf(mx, __shfl_down(mx, off));
    __shared__ float w[4];
    if ((t & 63) == 0) w[t >> 6] = mx;
    __syncthreads();
    if (t == 0) distmax[b] = fmaxf(fmaxf(w[0], w[1]), fmaxf(w[2], w[3]));
}

// ---------------- kernel 5: pass B — masked min partials ----------------
__global__ __launch_bounds__(256) void passB_kernel(const float* __restrict__ xknn,
                                                    const float* __restrict__ sq,
                                                    const float* __restrict__ density,
                                                    float* __restrict__ pmin) {
    const int ct = blockIdx.x, rt = blockIdx.y, b = blockIdx.z;
    const int tid = threadIdx.x;
    const int tx = tid & 15, ty = tid >> 4;
    __shared__ float As[16][68];
    __shared__ float Bs[16][68];
    __shared__ float redmn[64][16];

    const float* Ab = xknn + ((size_t)b * FF + rt * 64) * CH;
    const float* Bb = xknn + ((size_t)b * FF + ct * 64) * CH;
    const int lr = tid >> 2;
    const int lk = (tid & 3) * 4;
    float acc[4][4] = {};
    for (int kt = 0; kt < CH; kt += 16) {
        float4 a = *(const float4*)(Ab + (size_t)lr * CH + kt + lk);
        float4 bv = *(const float4*)(Bb + (size_t)lr * CH + kt + lk);
        __syncthreads();
        As[lk + 0][lr] = a.x;  As[lk + 1][lr] = a.y;  As[lk + 2][lr] = a.z;  As[lk + 3][lr] = a.w;
        Bs[lk + 0][lr] = bv.x; Bs[lk + 1][lr] = bv.y; Bs[lk + 2][lr] = bv.z; Bs[lk + 3][lr] = bv.w;
        __syncthreads();
        for (int kk = 0; kk < 16; ++kk) {
            const float4 av = *(const float4*)&As[kk][ty * 4];
            const float4 bw = *(const float4*)&Bs[kk][tx * 4];
            const float am[4] = {av.x, av.y, av.z, av.w};
            const float bn[4] = {bw.x, bw.y, bw.z, bw.w};
            for (int m = 0; m < 4; ++m)
                for (int n = 0; n < 4; ++n)
                    acc[m][n] = fmaf(am[m], bn[n], acc[m][n]);
        }
    }
    float sqa[4], sqb[4], dr[4], dc[4];
    for (int m = 0; m < 4; ++m) {
        sqa[m] = sq[b * FF + rt * 64 + ty * 4 + m];
        dr[m] = density[b * FF + rt * 64 + ty * 4 + m];
    }
    for (int n = 0; n < 4; ++n) {
        sqb[n] = sq[b * FF + ct * 64 + tx * 4 + n];
        dc[n] = density[b * FF + ct * 64 + tx * 4 + n];
    }
    for (int m = 0; m < 4; ++m) {
        float mn = FLT_MAX;
        for (int n = 0; n < 4; ++n) {
            float d2 = sqa[m] + sqb[n] - 2.0f * acc[m][n];
            float dist = sqrtf(fmaxf(d2, 0.0f)) / SQRT_C;
            if (dc[n] > dr[m]) mn = fminf(mn, dist);
        }
        redmn[ty * 4 + m][tx] = mn;
    }
    __syncthreads();
    if (tid < 64) {
        float mn = FLT_MAX;
        for (int j = 0; j < 16; ++j) mn = fminf(mn, redmn[tid][j]);
        const int row = rt * 64 + tid;
        pmin[((size_t)b * FF + row) * NT + ct] = mn;
    }
}

// ---------------- kernel 6: combine min partials -> score ----------------
__global__ __launch_bounds__(256) void reduceB_kernel(const float* __restrict__ pmin,
                                                      const float* __restrict__ density,
                                                      const float* __restrict__ distmax,
                                                      float* __restrict__ score) {
    const int r = blockIdx.x * 256 + threadIdx.x;
    if (r >= BB * FF) return;
    float mn = FLT_MAX;
    for (int j = 0; j < NT; ++j) mn = fminf(mn, pmin[(size_t)r * NT + j]);
    const int b = r >> 10;
    if (mn == FLT_MAX) mn = distmax[b];   // all-masked row (global density max)
    score[r] = mn * density[r];
}

// ---------------- kernel 7: top-81 + ascending sort ----------------
__global__ __launch_bounds__(64) void topk_kernel(const float* __restrict__ score,
                                                  int* __restrict__ selsort) {
    const int b = blockIdx.x, lane = threadIdx.x;
    float s[16];
    const float* sb = score + b * FF;
    for (int j = 0; j < 16; ++j) s[j] = sb[lane * 16 + j];
    __shared__ int sel[TOK];
    for (int it = 0; it < TOK; ++it) {
        float best = -FLT_MAX; int bi = 0;
        for (int j = 0; j < 16; ++j) {
            if (s[j] > best) { best = s[j]; bi = lane * 16 + j; }   // strict > keeps lowest idx
        }
        for (int off = 1; off < 64; off <<= 1) {
            float ob = __shfl_xor(best, off);
            int oi = __shfl_xor(bi, off);
            if (ob > best || (ob == best && oi < bi)) { best = ob; bi = oi; }
        }
        if ((bi >> 4) == lane) s[bi & 15] = -FLT_MAX;
        if (lane == 0) sel[it] = bi;
    }
    __syncthreads();
    for (int t = lane; t < TOK; t += 64) {
        const int v = sel[t];
        int rank = 0;
        for (int j = 0; j < TOK; ++j) rank += (sel[j] < v);
        selsort[b * TOK + rank] = v;
    }
}

// ---------------- kernel 8: gather + pos-embed ----------------
__global__ __launch_bounds__(256) void gather_kernel(const float* __restrict__ x,
                                                     const float* __restrict__ pos,
                                                     const int* __restrict__ selsort,
                                                     float* __restrict__ out) {
    const size_t i = (size_t)blockIdx.x * 256 + threadIdx.x;   // float4 index
    const size_t total = (size_t)BB * TOK * NJ * (CH / 4);
    if (i >= total) return;
    const int c4 = (int)(i & (CH / 4 - 1));
    size_t r = i >> 7;                 // CH/4 = 128
    const int n = (int)(r % NJ); r /= NJ;
    const int t = (int)(r % TOK);
    const int b = (int)(r / TOK);
    const int f = selsort[b * TOK + t];
    float4 v = *(const float4*)(x + (((size_t)(b * FF + f)) * NJ + n) * CH + c4 * 4);
    const float4 p = *(const float4*)(pos + (size_t)t * CH + c4 * 4);
    v.x += p.x; v.y += p.y; v.z += p.z; v.w += p.w;
    *(float4*)(out + i * 4) = v;
}

extern "C" void kernel_launch(void* const* d_in, const int* in_sizes, int n_in,
                              void* d_out, int out_size, void* d_ws, size_t ws_size,
                              hipStream_t stream) {
    const float* x     = (const float*)d_in[0];
    const float* pos   = (const float*)d_in[1];
    const float* noise = (const float*)d_in[2];
    // d_in[3] = current_layer, always == LAYER_INDEX in this harness
    float* out = (float*)d_out;

    float*  xknn    = (float*)d_ws;                         // B*F*C      = 4,194,304 f
    float*  sq      = xknn + (size_t)BB * FF * CH;          // B*F        = 8192 f
    float2* p2      = (float2*)(sq + BB * FF);              // B*F*NT f2  = 131,072 f2
    float*  pmax    = (float*)(p2 + (size_t)BB * FF * NT);  // B*F*NT
    float*  density = pmax + (size_t)BB * FF * NT;          // B*F
    float*  rowmax  = density + BB * FF;                    // B*F
    float*  distmax = rowmax + BB * FF;                     // B
    float*  pminB   = distmax + 8;                          // B*F*NT
    float*  score   = pminB + (size_t)BB * FF * NT;         // B*F
    int*    selsort = (int*)(score + BB * FF);              // B*TOK
    // total ~19.5 MB of ws

    pool_kernel<<<BB * FF, 128, 0, stream>>>(x, xknn, sq);
    dim3 g(NT, NT, BB);
    passA_kernel<<<g, 256, 0, stream>>>(xknn, sq, p2, pmax);
    reduceA_kernel<<<(BB * FF) / 256, 256, 0, stream>>>(p2, pmax, noise, density, rowmax);
    batchmax_kernel<<<BB, 256, 0, stream>>>(rowmax, distmax);
    passB_kernel<<<g, 256, 0, stream>>>(xknn, sq, density, pminB);
    reduceB_kernel<<<(BB * FF) / 256, 256, 0, stream>>>(pminB, density, distmax, score);
    topk_kernel<<<BB, 64, 0, stream>>>(score, selsort);
    const int gtot = (int)(((size_t)BB * TOK * NJ * (CH / 4) + 255) / 256);
    gather_kernel<<<gtot, 256, 0, stream>>>(x, pos, selsort, out);
}

// Round 2
// 594.664 us; speedup vs baseline: 1.2036x; 1.2036x over previous
//
#include <hip/hip_runtime.h>
#include <math.h>
#include <float.h>

#define BB 8
#define FF 1024
#define NJ 17
#define CH 512
#define TOK 81
#define TS 128           // GEMM tile size
#define BK 16            // k-slab
#define SQRT_C 22.627416997969522f   // sqrt(512)

// ---------------- kernel 1: mean over joints + row sumsq ----------------
__global__ __launch_bounds__(128) void pool_kernel(const float* __restrict__ x,
                                                   float* __restrict__ xknn,
                                                   float* __restrict__ sq) {
    const int row = blockIdx.x;          // b*FF + f
    const int t = threadIdx.x;           // 0..127, each owns 4 channels
    const float* px = x + (size_t)row * NJ * CH + t * 4;
    float4 acc = make_float4(0.f, 0.f, 0.f, 0.f);
    #pragma unroll
    for (int n = 0; n < NJ; ++n) {
        const float4 v = *(const float4*)(px + (size_t)n * CH);
        acc.x += v.x; acc.y += v.y; acc.z += v.z; acc.w += v.w;
    }
    acc.x /= 17.0f; acc.y /= 17.0f; acc.z /= 17.0f; acc.w /= 17.0f;
    *(float4*)(xknn + (size_t)row * CH + t * 4) = acc;
    float s = acc.x * acc.x + acc.y * acc.y + acc.z * acc.z + acc.w * acc.w;
    #pragma unroll
    for (int off = 32; off > 0; off >>= 1) s += __shfl_down(s, off);
    __shared__ float wsum[2];
    if ((t & 63) == 0) wsum[t >> 6] = s;
    __syncthreads();
    if (t == 0) sq[row] = wsum[0] + wsum[1];
}

__device__ inline void merge2(float& lo0, float& lo1, float c0, float c1) {
    // two smallest of {lo0<=lo1} U {c0<=c1}
    float n0 = fminf(lo0, c0);
    float n1 = fminf(fmaxf(lo0, c0), fminf(lo1, c1));
    lo0 = n0; lo1 = n1;
}

// ---------------- kernel 2: GEMM 128x128 tile, 8x8/thread, stores dist ------
__global__ __launch_bounds__(256) void passA_kernel(const float* __restrict__ xknn,
                                                    const float* __restrict__ sq,
                                                    float* __restrict__ dist) {
    const int ct = blockIdx.x, rt = blockIdx.y, b = blockIdx.z;
    const int tid = threadIdx.x;
    const int tx = tid & 15, ty = tid >> 4;       // 16x16 thread grid, 8x8 each
    __shared__ float As[BK][132];                 // k-major (transposed), +4 pad
    __shared__ float Bs[BK][132];

    const float* Ab = xknn + ((size_t)b * FF + rt * TS) * CH;
    const float* Bb = xknn + ((size_t)b * FF + ct * TS) * CH;
    const int lrow = tid >> 1;          // 0..127
    const int lk   = (tid & 1) * 8;     // 0 or 8

    // prefetch slab kt=0 into registers
    float4 a0 = *(const float4*)(Ab + (size_t)lrow * CH + lk);
    float4 a1 = *(const float4*)(Ab + (size_t)lrow * CH + lk + 4);
    float4 b0 = *(const float4*)(Bb + (size_t)lrow * CH + lk);
    float4 b1 = *(const float4*)(Bb + (size_t)lrow * CH + lk + 4);

    float acc[8][8] = {};
    for (int kt = 0; kt < CH; kt += BK) {
        __syncthreads();
        As[lk + 0][lrow] = a0.x; As[lk + 1][lrow] = a0.y;
        As[lk + 2][lrow] = a0.z; As[lk + 3][lrow] = a0.w;
        As[lk + 4][lrow] = a1.x; As[lk + 5][lrow] = a1.y;
        As[lk + 6][lrow] = a1.z; As[lk + 7][lrow] = a1.w;
        Bs[lk + 0][lrow] = b0.x; Bs[lk + 1][lrow] = b0.y;
        Bs[lk + 2][lrow] = b0.z; Bs[lk + 3][lrow] = b0.w;
        Bs[lk + 4][lrow] = b1.x; Bs[lk + 5][lrow] = b1.y;
        Bs[lk + 6][lrow] = b1.z; Bs[lk + 7][lrow] = b1.w;
        __syncthreads();
        if (kt + BK < CH) {             // prefetch next slab while computing
            const int ko = kt + BK + lk;
            a0 = *(const float4*)(Ab + (size_t)lrow * CH + ko);
            a1 = *(const float4*)(Ab + (size_t)lrow * CH + ko + 4);
            b0 = *(const float4*)(Bb + (size_t)lrow * CH + ko);
            b1 = *(const float4*)(Bb + (size_t)lrow * CH + ko + 4);
        }
        #pragma unroll
        for (int kk = 0; kk < BK; ++kk) {
            const float4 av0 = *(const float4*)&As[kk][ty * 8];
            const float4 av1 = *(const float4*)&As[kk][ty * 8 + 4];
            const float4 bv0 = *(const float4*)&Bs[kk][tx * 8];
            const float4 bv1 = *(const float4*)&Bs[kk][tx * 8 + 4];
            const float am[8] = {av0.x, av0.y, av0.z, av0.w, av1.x, av1.y, av1.z, av1.w};
            const float bn[8] = {bv0.x, bv0.y, bv0.z, bv0.w, bv1.x, bv1.y, bv1.z, bv1.w};
            #pragma unroll
            for (int m = 0; m < 8; ++m)
                #pragma unroll
                for (int n = 0; n < 8; ++n)
                    acc[m][n] = fmaf(am[m], bn[n], acc[m][n]);
        }
    }

    // epilogue: d2 -> dist, store tile
    const int row0 = rt * TS + ty * 8;
    const int col0 = ct * TS + tx * 8;
    float sqb[8];
    #pragma unroll
    for (int n = 0; n < 8; ++n) sqb[n] = sq[b * FF + col0 + n];
    #pragma unroll
    for (int m = 0; m < 8; ++m) {
        const float sa = sq[b * FF + row0 + m];
        float d[8];
        #pragma unroll
        for (int n = 0; n < 8; ++n) {
            float d2 = sa + sqb[n] - 2.0f * acc[m][n];
            d[n] = sqrtf(fmaxf(d2, 0.0f)) / SQRT_C;
        }
        float* dst = dist + ((size_t)b * FF + row0 + m) * FF + col0;
        *(float4*)(dst)     = make_float4(d[0], d[1], d[2], d[3]);
        *(float4*)(dst + 4) = make_float4(d[4], d[5], d[6], d[7]);
    }
}

// ---------------- kernel 3: per-row two-smallest + rowmax -> density --------
__global__ __launch_bounds__(256) void rowstat_kernel(const float* __restrict__ dist,
                                                      const float* __restrict__ noise,
                                                      float* __restrict__ density,
                                                      float* __restrict__ rowmax) {
    const int r = blockIdx.x * 4 + (threadIdx.x >> 6);    // one wave per row
    const int lane = threadIdx.x & 63;
    const float* dr = dist + (size_t)r * FF;
    float lo0 = FLT_MAX, lo1 = FLT_MAX, mx = -FLT_MAX;
    #pragma unroll
    for (int j = 0; j < FF / 64; ++j) {
        const float d = dr[lane + j * 64];
        mx = fmaxf(mx, d);
        merge2(lo0, lo1, d, FLT_MAX);
    }
    #pragma unroll
    for (int off = 32; off > 0; off >>= 1) {
        const float o0 = __shfl_down(lo0, off);
        const float o1 = __shfl_down(lo1, off);
        const float om = __shfl_down(mx, off);
        merge2(lo0, lo1, o0, o1);
        mx = fmaxf(mx, om);
    }
    if (lane == 0) {
        density[r] = expf(-0.5f * (lo0 * lo0 + lo1 * lo1)) + noise[r] * 1e-6f;
        rowmax[r] = mx;
    }
}

// ---------------- kernel 4: per-batch max distance ----------------
__global__ __launch_bounds__(256) void batchmax_kernel(const float* __restrict__ rowmax,
                                                       float* __restrict__ distmax) {
    const int b = blockIdx.x, t = threadIdx.x;
    float mx = -FLT_MAX;
    for (int j = t; j < FF; j += 256) mx = fmaxf(mx, rowmax[b * FF + j]);
    #pragma unroll
    for (int off = 32; off > 0; off >>= 1) mx = fmaxf(mx, __shfl_down(mx, off));
    __shared__ float w[4];
    if ((t & 63) == 0) w[t >> 6] = mx;
    __syncthreads();
    if (t == 0) distmax[b] = fmaxf(fmaxf(w[0], w[1]), fmaxf(w[2], w[3]));
}

// ---------------- kernel 5: per-row masked min -> score ----------------
__global__ __launch_bounds__(256) void scoremin_kernel(const float* __restrict__ dist,
                                                       const float* __restrict__ density,
                                                       const float* __restrict__ distmax,
                                                       float* __restrict__ score) {
    const int r = blockIdx.x * 4 + (threadIdx.x >> 6);    // one wave per row
    const int lane = threadIdx.x & 63;
    const int b = r >> 10;
    const float* dr = dist + (size_t)r * FF;
    const float* db = density + (size_t)b * FF;
    const float dme = density[r];
    float mn = FLT_MAX;
    #pragma unroll
    for (int j = 0; j < FF / 64; ++j) {
        const int c = lane + j * 64;
        const float d = dr[c];
        const float dj = db[c];
        if (dj > dme) mn = fminf(mn, d);
    }
    #pragma unroll
    for (int off = 32; off > 0; off >>= 1) mn = fminf(mn, __shfl_down(mn, off));
    if (lane == 0) {
        if (mn == FLT_MAX) mn = distmax[b];   // all-masked row (batch density max)
        score[r] = mn * dme;
    }
}

// ---------------- kernel 6: top-81 + ascending sort ----------------
__global__ __launch_bounds__(64) void topk_kernel(const float* __restrict__ score,
                                                  int* __restrict__ selsort) {
    const int b = blockIdx.x, lane = threadIdx.x;
    float s[16];
    const float* sb = score + b * FF;
    #pragma unroll
    for (int j = 0; j < 16; ++j) s[j] = sb[lane * 16 + j];
    __shared__ int sel[TOK];
    for (int it = 0; it < TOK; ++it) {
        float best = -FLT_MAX; int bi = 0;
        #pragma unroll
        for (int j = 0; j < 16; ++j) {
            if (s[j] > best) { best = s[j]; bi = lane * 16 + j; }   // strict > keeps lowest idx
        }
        #pragma unroll
        for (int off = 1; off < 64; off <<= 1) {
            float ob = __shfl_xor(best, off);
            int oi = __shfl_xor(bi, off);
            if (ob > best || (ob == best && oi < bi)) { best = ob; bi = oi; }
        }
        if ((bi >> 4) == lane) s[bi & 15] = -FLT_MAX;
        if (lane == 0) sel[it] = bi;
    }
    __syncthreads();
    for (int t = lane; t < TOK; t += 64) {
        const int v = sel[t];
        int rank = 0;
        for (int j = 0; j < TOK; ++j) rank += (sel[j] < v);
        selsort[b * TOK + rank] = v;
    }
}

// ---------------- kernel 7: gather + pos-embed ----------------
__global__ __launch_bounds__(256) void gather_kernel(const float* __restrict__ x,
                                                     const float* __restrict__ pos,
                                                     const int* __restrict__ selsort,
                                                     float* __restrict__ out) {
    const size_t i = (size_t)blockIdx.x * 256 + threadIdx.x;   // float4 index
    const size_t total = (size_t)BB * TOK * NJ * (CH / 4);
    if (i >= total) return;
    const int c4 = (int)(i & (CH / 4 - 1));
    size_t r = i >> 7;                 // CH/4 = 128
    const int n = (int)(r % NJ); r /= NJ;
    const int t = (int)(r % TOK);
    const int b = (int)(r / TOK);
    const int f = selsort[b * TOK + t];
    float4 v = *(const float4*)(x + (((size_t)(b * FF + f)) * NJ + n) * CH + c4 * 4);
    const float4 p = *(const float4*)(pos + (size_t)t * CH + c4 * 4);
    v.x += p.x; v.y += p.y; v.z += p.z; v.w += p.w;
    *(float4*)(out + i * 4) = v;
}

extern "C" void kernel_launch(void* const* d_in, const int* in_sizes, int n_in,
                              void* d_out, int out_size, void* d_ws, size_t ws_size,
                              hipStream_t stream) {
    const float* x     = (const float*)d_in[0];
    const float* pos   = (const float*)d_in[1];
    const float* noise = (const float*)d_in[2];
    // d_in[3] = current_layer, always == LAYER_INDEX in this harness
    float* out = (float*)d_out;

    float* xknn    = (float*)d_ws;                        // B*F*C   = 4,194,304 f (16 MB)
    float* dist    = xknn + (size_t)BB * FF * CH;         // B*F*F   = 8,388,608 f (33.5 MB)
    float* sq      = dist + (size_t)BB * FF * FF;         // B*F
    float* density = sq + BB * FF;                        // B*F
    float* rowmax  = density + BB * FF;                   // B*F
    float* distmax = rowmax + BB * FF;                    // B
    float* score   = distmax + 8;                         // B*F
    int*   selsort = (int*)(score + BB * FF);             // B*TOK
    // total ~50 MB of ws (ws is ~1 GB per the poison-fill size)

    pool_kernel<<<BB * FF, 128, 0, stream>>>(x, xknn, sq);
    dim3 g(FF / TS, FF / TS, BB);                         // (8, 8, 8)
    passA_kernel<<<g, 256, 0, stream>>>(xknn, sq, dist);
    rowstat_kernel<<<(BB * FF) / 4, 256, 0, stream>>>(dist, noise, density, rowmax);
    batchmax_kernel<<<BB, 256, 0, stream>>>(rowmax, distmax);
    scoremin_kernel<<<(BB * FF) / 4, 256, 0, stream>>>(dist, density, distmax, score);
    topk_kernel<<<BB, 64, 0, stream>>>(score, selsort);
    const int gtot = (int)(((size_t)BB * TOK * NJ * (CH / 4) + 255) / 256);
    gather_kernel<<<gtot, 256, 0, stream>>>(x, pos, selsort, out);
}

// Round 4
// 527.011 us; speedup vs baseline: 1.3581x; 1.1284x over previous
//
#include <hip/hip_runtime.h>
#include <math.h>
#include <float.h>

#define BB 8
#define FF 1024
#define NJ 17
#define CH 512
#define TOK 81
#define RCP_SQRT_C 0.04419417382415922f   // 1/sqrt(512)
#define LP 133                            // LDS row pad (stride%32=5, conflict-free col reads)

typedef short bf16x8 __attribute__((ext_vector_type(8)));   // 8 bf16 = 4 VGPRs
typedef float f32x16 __attribute__((ext_vector_type(16)));  // 32x32 MFMA acc

static __device__ inline unsigned short f2bf(float f) {
    __bf16 h = (__bf16)f;                       // RNE
    return __builtin_bit_cast(unsigned short, h);
}
static __device__ inline float bf2f(unsigned short u) {
    return (float)__builtin_bit_cast(__bf16, u);
}

// frag layout: [b][s(32)][h(2)][f(1024)][j(8)] bf16, uint4 index ((b*32+s)*2+h)*1024 + f

// ---------------- kernel 1: mean over joints + sumsq + hi/lo frag write -------
__global__ __launch_bounds__(256) void pool_kernel(const float* __restrict__ x,
                                                   uint4* __restrict__ fhi,
                                                   uint4* __restrict__ flo,
                                                   float* __restrict__ sq) {
    const int t = threadIdx.x;
    const int wid = t >> 6, lane = t & 63;
    const int row0 = blockIdx.x * 4;            // 4 rows per block, one wave per row
    const int row = row0 + wid;
    const int b = row >> 10, f0 = row0 & 1023;
    const float* px = x + (size_t)row * NJ * CH + lane * 8;
    float a[8] = {};
    #pragma unroll
    for (int n = 0; n < NJ; ++n) {
        const float4 v0 = *(const float4*)(px + (size_t)n * CH);
        const float4 v1 = *(const float4*)(px + (size_t)n * CH + 4);
        a[0] += v0.x; a[1] += v0.y; a[2] += v0.z; a[3] += v0.w;
        a[4] += v1.x; a[5] += v1.y; a[6] += v1.z; a[7] += v1.w;
    }
    float ssq = 0.f;
    unsigned short hi[8], lo[8];
    #pragma unroll
    for (int j = 0; j < 8; ++j) {
        const float m = a[j] / 17.0f;
        ssq += m * m;
        hi[j] = f2bf(m);
        lo[j] = f2bf(m - bf2f(hi[j]));
    }
    #pragma unroll
    for (int off = 32; off > 0; off >>= 1) ssq += __shfl_down(ssq, off);
    if (lane == 0) sq[row] = ssq;

    uint4 uh, ul;
    uh.x = (unsigned)hi[0] | ((unsigned)hi[1] << 16);
    uh.y = (unsigned)hi[2] | ((unsigned)hi[3] << 16);
    uh.z = (unsigned)hi[4] | ((unsigned)hi[5] << 16);
    uh.w = (unsigned)hi[6] | ((unsigned)hi[7] << 16);
    ul.x = (unsigned)lo[0] | ((unsigned)lo[1] << 16);
    ul.y = (unsigned)lo[2] | ((unsigned)lo[3] << 16);
    ul.z = (unsigned)lo[4] | ((unsigned)lo[5] << 16);
    ul.w = (unsigned)lo[6] | ((unsigned)lo[7] << 16);
    __shared__ uint4 sh_hi[256], sh_lo[256];
    sh_hi[lane * 4 + wid] = uh;
    sh_lo[lane * 4 + wid] = ul;
    __syncthreads();
    const int k8 = t >> 2, fpr = t & 3;         // k8 chunk, frame-in-block
    const int s = k8 >> 1, h = k8 & 1;
    const size_t o = (((size_t)b * 32 + s) * 2 + h) * 1024 + f0 + fpr;
    fhi[o] = sh_hi[t];
    flo[o] = sh_lo[t];
}

// ------- kernel 2: split-bf16 MFMA Gram, upper-tri tiles, mirrored store -------
__global__ __launch_bounds__(256) void dist_kernel(const uint4* __restrict__ fhi,
                                                   const uint4* __restrict__ flo,
                                                   const float* __restrict__ sq,
                                                   float* __restrict__ dist) {
    // map blockIdx.x (0..35) -> upper-triangular tile (rt <= ct)
    int tri = blockIdx.x, rt = 0;
    while (tri >= 8 - rt) { tri -= 8 - rt; ++rt; }
    const int ct = rt + tri;
    const bool diag = (rt == ct);
    const int b = blockIdx.z;
    const int tid = threadIdx.x;
    const int w = tid >> 6, lane = tid & 63;
    const int R = rt * 128 + (w & 1) * 64;      // wave rows (2 tiles of 32)
    const int C = ct * 128 + (w >> 1) * 64;     // wave cols
    const int h = lane >> 5, fr = lane & 31;

    size_t a0 = ((size_t)b * 64 + h) * 1024 + R + fr;   // uint4 units; +2048 per k16-step
    size_t b0 = ((size_t)b * 64 + h) * 1024 + C + fr;

    f32x16 acc00, acc01, acc10, acc11;
    #pragma unroll
    for (int i = 0; i < 16; ++i) { acc00[i] = 0.f; acc01[i] = 0.f; acc10[i] = 0.f; acc11[i] = 0.f; }

    bf16x8 A0h = *(const bf16x8*)(fhi + a0), A1h = *(const bf16x8*)(fhi + a0 + 32);
    bf16x8 A0l = *(const bf16x8*)(flo + a0), A1l = *(const bf16x8*)(flo + a0 + 32);
    bf16x8 B0h = *(const bf16x8*)(fhi + b0), B1h = *(const bf16x8*)(fhi + b0 + 32);
    bf16x8 B0l = *(const bf16x8*)(flo + b0), B1l = *(const bf16x8*)(flo + b0 + 32);

    #pragma unroll 4
    for (int s = 0; s < 32; ++s) {
        const bf16x8 cA0h = A0h, cA1h = A1h, cA0l = A0l, cA1l = A1l;
        const bf16x8 cB0h = B0h, cB1h = B1h, cB0l = B0l, cB1l = B1l;
        if (s < 31) {
            a0 += 2048; b0 += 2048;
            A0h = *(const bf16x8*)(fhi + a0); A1h = *(const bf16x8*)(fhi + a0 + 32);
            A0l = *(const bf16x8*)(flo + a0); A1l = *(const bf16x8*)(flo + a0 + 32);
            B0h = *(const bf16x8*)(fhi + b0); B1h = *(const bf16x8*)(fhi + b0 + 32);
            B0l = *(const bf16x8*)(flo + b0); B1l = *(const bf16x8*)(flo + b0 + 32);
        }
        acc00 = __builtin_amdgcn_mfma_f32_32x32x16_bf16(cA0h, cB0h, acc00, 0, 0, 0);
        acc01 = __builtin_amdgcn_mfma_f32_32x32x16_bf16(cA0h, cB1h, acc01, 0, 0, 0);
        acc10 = __builtin_amdgcn_mfma_f32_32x32x16_bf16(cA1h, cB0h, acc10, 0, 0, 0);
        acc11 = __builtin_amdgcn_mfma_f32_32x32x16_bf16(cA1h, cB1h, acc11, 0, 0, 0);
        acc00 = __builtin_amdgcn_mfma_f32_32x32x16_bf16(cA0h, cB0l, acc00, 0, 0, 0);
        acc01 = __builtin_amdgcn_mfma_f32_32x32x16_bf16(cA0h, cB1l, acc01, 0, 0, 0);
        acc10 = __builtin_amdgcn_mfma_f32_32x32x16_bf16(cA1h, cB0l, acc10, 0, 0, 0);
        acc11 = __builtin_amdgcn_mfma_f32_32x32x16_bf16(cA1h, cB1l, acc11, 0, 0, 0);
        acc00 = __builtin_amdgcn_mfma_f32_32x32x16_bf16(cA0l, cB0h, acc00, 0, 0, 0);
        acc01 = __builtin_amdgcn_mfma_f32_32x32x16_bf16(cA0l, cB1h, acc01, 0, 0, 0);
        acc10 = __builtin_amdgcn_mfma_f32_32x32x16_bf16(cA1l, cB0h, acc10, 0, 0, 0);
        acc11 = __builtin_amdgcn_mfma_f32_32x32x16_bf16(cA1l, cB1h, acc11, 0, 0, 0);
    }

    // ---- epilogue: two phases through a 64x128 LDS stage; mirrored stores ----
    __shared__ float lds[64 * LP];
    const int bF = b * FF;
    const int R0 = rt * 128, C0 = ct * 128;
    const float sqc0 = sq[bF + C + fr], sqc1 = sq[bF + C + fr + 32];
    const int lcb = (w >> 1) * 64 + fr;         // local col base in 0..127

    #pragma unroll
    for (int p = 0; p < 2; ++p) {
        if ((w & 1) == p) {                     // this wave's rows belong to phase p
            #pragma unroll
            for (int reg = 0; reg < 16; ++reg) {
                const int rp = 4 * h + (reg & 3) + 8 * (reg >> 2);   // 0..31
                const float sqr0 = sq[bF + R + rp];
                const float sqr1 = sq[bF + R + rp + 32];
                lds[rp * LP + lcb] =
                    sqrtf(fmaxf(sqr0 + sqc0 - 2.0f * acc00[reg], 0.f)) * RCP_SQRT_C;
                lds[rp * LP + lcb + 32] =
                    sqrtf(fmaxf(sqr0 + sqc1 - 2.0f * acc01[reg], 0.f)) * RCP_SQRT_C;
                lds[(rp + 32) * LP + lcb] =
                    sqrtf(fmaxf(sqr1 + sqc0 - 2.0f * acc10[reg], 0.f)) * RCP_SQRT_C;
                lds[(rp + 32) * LP + lcb + 32] =
                    sqrtf(fmaxf(sqr1 + sqc1 - 2.0f * acc11[reg], 0.f)) * RCP_SQRT_C;
            }
        }
        __syncthreads();
        if (!diag) {
            // direct: rows R0+p*64+lr, cols C0..C0+127 (coalesced)
            for (int q = tid; q < 64 * 128; q += 256) {
                const int lr = q >> 7, c = q & 127;
                dist[((size_t)bF + R0 + p * 64 + lr) * FF + C0 + c] = lds[lr * LP + c];
            }
            // mirror: rows C0+c, cols R0+p*64+lr (lanes along lr -> coalesced)
            for (int q = tid; q < 64 * 128; q += 256) {
                const int lr = q & 63, c = q >> 6;
                dist[((size_t)bF + C0 + c) * FF + R0 + p * 64 + lr] = lds[lr * LP + c];
            }
        } else if (p == 0) {
            // rows i=0..63, all cols: canonical upper value (0 on diagonal)
            for (int q = tid; q < 64 * 128; q += 256) {
                const int i = q >> 7, j = q & 127;
                const float v = (i == j) ? 0.f : (i < j ? lds[i * LP + j] : lds[j * LP + i]);
                dist[((size_t)bF + R0 + i) * FF + C0 + j] = v;
            }
            // rows i=64..127, cols j=0..63: mirror of staged (j, i)
            for (int q = tid; q < 64 * 64; q += 256) {
                const int i = 64 + (q >> 6), j = q & 63;
                dist[((size_t)bF + R0 + i) * FF + C0 + j] = lds[j * LP + i];
            }
        } else {
            // rows i=64..127, cols j=64..127: canonical within staged rows 64..127
            for (int q = tid; q < 64 * 64; q += 256) {
                const int i = 64 + (q >> 6), j = 64 + (q & 63);
                const float v = (i == j) ? 0.f
                               : (i < j ? lds[(i - 64) * LP + j] : lds[(j - 64) * LP + i]);
                dist[((size_t)bF + R0 + i) * FF + C0 + j] = v;
            }
        }
        __syncthreads();
    }
}

__device__ inline void merge2(float& lo0, float& lo1, float c0, float c1) {
    float n0 = fminf(lo0, c0);
    float n1 = fminf(fmaxf(lo0, c0), fminf(lo1, c1));
    lo0 = n0; lo1 = n1;
}

// ---------------- kernel 3: per-row two-smallest + rowmax -> density --------
__global__ __launch_bounds__(256) void rowstat_kernel(const float* __restrict__ dist,
                                                      const float* __restrict__ noise,
                                                      float* __restrict__ density,
                                                      float* __restrict__ rowmax) {
    const int r = blockIdx.x * 4 + (threadIdx.x >> 6);
    const int lane = threadIdx.x & 63;
    const float* dr = dist + (size_t)r * FF;
    float lo0 = FLT_MAX, lo1 = FLT_MAX, mx = -FLT_MAX;
    #pragma unroll
    for (int j = 0; j < FF / 64; ++j) {
        const float d = dr[lane + j * 64];
        mx = fmaxf(mx, d);
        merge2(lo0, lo1, d, FLT_MAX);
    }
    #pragma unroll
    for (int off = 32; off > 0; off >>= 1) {
        const float o0 = __shfl_down(lo0, off);
        const float o1 = __shfl_down(lo1, off);
        const float om = __shfl_down(mx, off);
        merge2(lo0, lo1, o0, o1);
        mx = fmaxf(mx, om);
    }
    if (lane == 0) {
        density[r] = expf(-0.5f * (lo0 * lo0 + lo1 * lo1)) + noise[r] * 1e-6f;
        rowmax[r] = mx;
    }
}

// ---------------- kernel 4: per-batch max distance ----------------
__global__ __launch_bounds__(256) void batchmax_kernel(const float* __restrict__ rowmax,
                                                       float* __restrict__ distmax) {
    const int b = blockIdx.x, t = threadIdx.x;
    float mx = -FLT_MAX;
    for (int j = t; j < FF; j += 256) mx = fmaxf(mx, rowmax[b * FF + j]);
    #pragma unroll
    for (int off = 32; off > 0; off >>= 1) mx = fmaxf(mx, __shfl_down(mx, off));
    __shared__ float w[4];
    if ((t & 63) == 0) w[t >> 6] = mx;
    __syncthreads();
    if (t == 0) distmax[b] = fmaxf(fmaxf(w[0], w[1]), fmaxf(w[2], w[3]));
}

// ---------------- kernel 5: per-row masked min -> score ----------------
__global__ __launch_bounds__(256) void scoremin_kernel(const float* __restrict__ dist,
                                                       const float* __restrict__ density,
                                                       const float* __restrict__ distmax,
                                                       float* __restrict__ score) {
    const int r = blockIdx.x * 4 + (threadIdx.x >> 6);
    const int lane = threadIdx.x & 63;
    const int b = r >> 10;
    const float* dr = dist + (size_t)r * FF;
    const float* db = density + (size_t)b * FF;
    const float dme = density[r];
    float mn = FLT_MAX;
    #pragma unroll
    for (int j = 0; j < FF / 64; ++j) {
        const int c = lane + j * 64;
        if (db[c] > dme) mn = fminf(mn, dr[c]);
    }
    #pragma unroll
    for (int off = 32; off > 0; off >>= 1) mn = fminf(mn, __shfl_down(mn, off));
    if (lane == 0) {
        if (mn == FLT_MAX) mn = distmax[b];
        score[r] = mn * dme;
    }
}

// ---------------- kernel 6: top-81 + ascending index sort ----------------
__global__ __launch_bounds__(64) void topk_kernel(const float* __restrict__ score,
                                                  int* __restrict__ selsort) {
    const int b = blockIdx.x, lane = threadIdx.x;
    float s[16];
    const float* sb = score + b * FF;
    #pragma unroll
    for (int j = 0; j < 16; ++j) s[j] = sb[lane * 16 + j];
    __shared__ int sel[TOK];
    for (int it = 0; it < TOK; ++it) {
        float best = -FLT_MAX; int bi = 0;
        #pragma unroll
        for (int j = 0; j < 16; ++j) {
            if (s[j] > best) { best = s[j]; bi = lane * 16 + j; }
        }
        #pragma unroll
        for (int off = 1; off < 64; off <<= 1) {
            float ob = __shfl_xor(best, off);
            int oi = __shfl_xor(bi, off);
            if (ob > best || (ob == best && oi < bi)) { best = ob; bi = oi; }
        }
        if ((bi >> 4) == lane) s[bi & 15] = -FLT_MAX;
        if (lane == 0) sel[it] = bi;
    }
    __syncthreads();
    for (int t = lane; t < TOK; t += 64) {
        const int v = sel[t];
        int rank = 0;
        for (int j = 0; j < TOK; ++j) rank += (sel[j] < v);
        selsort[b * TOK + rank] = v;
    }
}

// ---------------- kernel 7: gather + pos-embed ----------------
__global__ __launch_bounds__(256) void gather_kernel(const float* __restrict__ x,
                                                     const float* __restrict__ pos,
                                                     const int* __restrict__ selsort,
                                                     float* __restrict__ out) {
    const size_t i = (size_t)blockIdx.x * 256 + threadIdx.x;
    const size_t total = (size_t)BB * TOK * NJ * (CH / 4);
    if (i >= total) return;
    const int c4 = (int)(i & (CH / 4 - 1));
    size_t r = i >> 7;
    const int n = (int)(r % NJ); r /= NJ;
    const int t = (int)(r % TOK);
    const int b = (int)(r / TOK);
    const int f = selsort[b * TOK + t];
    float4 v = *(const float4*)(x + (((size_t)(b * FF + f)) * NJ + n) * CH + c4 * 4);
    const float4 p = *(const float4*)(pos + (size_t)t * CH + c4 * 4);
    v.x += p.x; v.y += p.y; v.z += p.z; v.w += p.w;
    *(float4*)(out + i * 4) = v;
}

extern "C" void kernel_launch(void* const* d_in, const int* in_sizes, int n_in,
                              void* d_out, int out_size, void* d_ws, size_t ws_size,
                              hipStream_t stream) {
    const float* x     = (const float*)d_in[0];
    const float* pos   = (const float*)d_in[1];
    const float* noise = (const float*)d_in[2];
    float* out = (float*)d_out;

    uint4* fhi    = (uint4*)d_ws;                           // 8 MB
    uint4* flo    = fhi + (size_t)BB * 32 * 2 * 1024;       // 8 MB
    float* dist   = (float*)(flo + (size_t)BB * 32 * 2 * 1024);  // 33.5 MB
    float* sq     = dist + (size_t)BB * FF * FF;
    float* density = sq + BB * FF;
    float* rowmax  = density + BB * FF;
    float* distmax = rowmax + BB * FF;
    float* score   = distmax + 8;
    int*   selsort = (int*)(score + BB * FF);

    pool_kernel<<<(BB * FF) / 4, 256, 0, stream>>>(x, fhi, flo, sq);
    dim3 g(36, 1, BB);                                      // upper-tri 128x128 tiles
    dist_kernel<<<g, 256, 0, stream>>>(fhi, flo, sq, dist);
    rowstat_kernel<<<(BB * FF) / 4, 256, 0, stream>>>(dist, noise, density, rowmax);
    batchmax_kernel<<<BB, 256, 0, stream>>>(rowmax, distmax);
    scoremin_kernel<<<(BB * FF) / 4, 256, 0, stream>>>(dist, density, distmax, score);
    topk_kernel<<<BB, 64, 0, stream>>>(score, selsort);
    const int gtot = (int)(((size_t)BB * TOK * NJ * (CH / 4) + 255) / 256);
    gather_kernel<<<gtot, 256, 0, stream>>>(x, pos, selsort, out);
}